// Round 11
// baseline (721.737 us; speedup 1.0000x reference)
//
#include <hip/hip_runtime.h>
#include <hip/hip_bf16.h>
#include <math.h>

// Round-0 proven 128x128x64 2-barrier GEMM structure with A pre-packed in
// tile-packed layout [mblk][chunk][row][8]:
//  - global_load_lds staging fully linear/coalesced (1KB/wave/instr)
//  - LDS frag reads lane-contiguous -> 0 bank conflicts (R5 PMC: 6.29M -> 0)
//  - __launch_bounds__(256,4): 60+64=124 regs < 128 -> 4 blocks/CU (occ 37%)
// R10: front-end fused into ONE kernel (5 indep sections; was 5 launches of
// 192..4096 blocks serializing); gate merged into premul launch; bijective
// XCD swizzle on GEMM grids (B panels L2-resident per XCD; FETCH was 2.9x
// ideal from round-robin panel duplication).
// NOTE: 8-phase/double-buffer schedules REGRESSED 3x (R1/R2/R4: 180/156/160us
// vs 135us) — multi-block/CU overlap beats lockstep pipelining. Do not re-add.
#define BM 128
#define BN 128
#define BK 64

typedef __bf16 bf16x8_t __attribute__((ext_vector_type(8)));
typedef __bf16 bf16x4_t __attribute__((ext_vector_type(4)));
typedef float f32x16_t __attribute__((ext_vector_type(16)));

static __device__ __forceinline__ float bf2f(__bf16 b) {
    unsigned short s = __builtin_bit_cast(unsigned short, b);
    unsigned int u = ((unsigned int)s) << 16;
    return __builtin_bit_cast(float, u);
}
static __device__ __forceinline__ __bf16 f2bf(float f) {
    unsigned int u = __builtin_bit_cast(unsigned int, f);
    unsigned int r = (u + 0x7fffu + ((u >> 16) & 1u)) >> 16;
    return __builtin_bit_cast(__bf16, (unsigned short)r);
}
// GELU tanh-form, |err vs exact| ~1e-3 << 4e-2 tolerance.
static __device__ __forceinline__ float gelu_fast(float x) {
    const float s = x * (0.7978845608f + 0.0356774081f * x * x);
    const float e = __expf(-2.0f * s);
    return x * __builtin_amdgcn_rcpf(1.0f + e);
}

#define GLDS16(gp, lp)                                                                   \
    __builtin_amdgcn_global_load_lds((const __attribute__((address_space(1))) void*)(gp), \
                                     (__attribute__((address_space(3))) void*)(lp), 16, 0, 0)

// ---------------------------------------------------------------------------
// Device bodies for the fused front-end kernel.
// ---------------------------------------------------------------------------

// fp32 W[K][N] tile (64x64 at k0,n0) -> bf16 B'[K/8][N][8]; optional fused
// b1t[n] += sum_k bcat[k]*W[k][n] (+ b1[n] on k0==0 block).
template <bool DOBIAS>
static __device__ __forceinline__ void frag_body(const float* __restrict__ in,
                                                 __bf16* __restrict__ out,
                                                 int N, int k0, int n0, int tid,
                                                 float* tile /*64x65*/, float* pb /*4x64*/,
                                                 const float* __restrict__ vb,
                                                 const float* __restrict__ tb,
                                                 const float* __restrict__ b1e,
                                                 float* __restrict__ b1te) {
    const int r = tid >> 4, c4 = (tid & 15) * 4;
#pragma unroll
    for (int p = 0; p < 4; ++p) {
        const float4 v = *(const float4*)&in[(size_t)(k0 + r + p * 16) * N + n0 + c4];
        float* t = tile + (r + p * 16) * 65 + c4;
        t[0] = v.x; t[1] = v.y; t[2] = v.z; t[3] = v.w;
    }
    __syncthreads();
    if (DOBIAS) {
        const int n = tid & 63, kq = tid >> 6;
        float p = 0.f;
#pragma unroll
        for (int rr = 0; rr < 16; ++rr) {
            const int kg = k0 + kq * 16 + rr;            // wave-uniform -> s_load
            const float bv = (kg < 1024) ? vb[kg] : tb[kg - 1024];
            p += bv * tile[(kq * 16 + rr) * 65 + n];
        }
        pb[kq * 64 + n] = p;
    }
    const int c = tid >> 5, nn0 = (tid & 31) * 2;
#pragma unroll
    for (int t = 0; t < 2; ++t) {
        const int nn = nn0 + t;
        bf16x8_t v;
#pragma unroll
        for (int j = 0; j < 8; ++j) v[j] = f2bf(tile[(c * 8 + j) * 65 + nn]);
        *(bf16x8_t*)&out[((size_t)(k0 >> 3) + c) * N * 8 + (size_t)(n0 + nn) * 8] = v;
    }
    if (DOBIAS) {
        __syncthreads();
        if (tid < 64) {
            float s = pb[tid] + pb[64 + tid] + pb[128 + tid] + pb[192 + tid];
            if (k0 == 0) s += b1e[n0 + tid];
            atomicAdd(&b1te[n0 + tid], s);
        }
    }
}

// 128x64 fp32 tile (row stride srcLd) -> A-packed bf16 at dst (+ch*1024+row*8).
static __device__ __forceinline__ void castpack_body(const float* __restrict__ src,
                                                     int srcLd, __bf16* __restrict__ dst,
                                                     int tid, __bf16* lds /*8*1032*/) {
#pragma unroll
    for (int k = 0; k < 8; ++k) {
        const int f = tid + k * 256;
        const int row = f >> 4, c4 = f & 15;
        const float4 v = *(const float4*)(src + (size_t)row * srcLd + c4 * 4);
        __bf16* d = lds + (c4 >> 1) * 1032 + row * 8 + (c4 & 1) * 4;
        d[0] = f2bf(v.x); d[1] = f2bf(v.y); d[2] = f2bf(v.z); d[3] = f2bf(v.w);
    }
    __syncthreads();
#pragma unroll
    for (int k = 0; k < 4; ++k) {
        const int g = tid + k * 256;
        const int ch = g >> 7, row = g & 127;
        const bf16x8_t v = *(const bf16x8_t*)(lds + ch * 1032 + row * 8);
        *(bf16x8_t*)(dst + (size_t)ch * 1024 + row * 8) = v;
    }
}

// ---------------------------------------------------------------------------
// Fused front-end: [0,192) cast2(wbf) | [192,1728) cast_acat | [1728,5824)
// frag w1 (+b1t) | [5824,7872) frag w2 | [7872,9409) gcat. All independent.
// ---------------------------------------------------------------------------
__global__ __launch_bounds__(256) void front_kernel(
    const float* __restrict__ visual, const float* __restrict__ text,
    const float* __restrict__ vis_w, const float* __restrict__ txt_w,
    const float* __restrict__ w1, const float* __restrict__ w2,
    const float* __restrict__ vis_b, const float* __restrict__ txt_b,
    const float* __restrict__ b1,
    const float* __restrict__ gw, const float* __restrict__ gb,
    __bf16* __restrict__ wbf, __bf16* __restrict__ acat,
    __bf16* __restrict__ w1t, __bf16* __restrict__ w2t,
    float* __restrict__ b1t, float* __restrict__ gcat) {
    __shared__ __align__(16) float smem[64 * 65 + 256];   // 17.7 KB union
    const int id = blockIdx.x;
    const int tid = threadIdx.x;
    if (id < 192) {
        // cast2: fp32 [768][1024] x2 -> A-packed wbf
        __bf16* lds = (__bf16*)smem;
        const int m = id / 96, r2 = id % 96;
        const int mb = r2 >> 4, ct = r2 & 15;
        const int c0 = ct * 64;
        const float* src = (m ? txt_w : vis_w) + (size_t)mb * 128 * 1024 + c0;
        __bf16* dst = wbf + (size_t)m * 786432 + (size_t)mb * 131072 + (size_t)(c0 >> 3) * 1024;
        castpack_body(src, 1024, dst, tid, lds);
    } else if (id < 1728) {
        // cast_acat: visual|text -> A-packed acat
        __bf16* lds = (__bf16*)smem;
        const int i = id - 192;
        const int ct = i % 24, mb = i / 24;
        const int c0 = ct * 64;
        const float* src = (c0 < 768) ? visual + (size_t)mb * 128 * 768 + c0
                                      : text + (size_t)mb * 128 * 768 + (c0 - 768);
        __bf16* dst = acat + (size_t)mb * 196608 + (size_t)(c0 >> 3) * 1024;
        castpack_body(src, 768, dst, tid, lds);
    } else if (id < 5824) {
        // frag-pack w1 (K=2048,N=1024) + fused b1t reduce
        const int i = id - 1728;
        const int kx = i & 31, ny = (i >> 5) & 15, e = i >> 9;
        frag_body<true>(w1 + (size_t)e * 2048 * 1024, w1t + (size_t)e * 2048 * 1024,
                        1024, kx * 64, ny * 64, tid, smem, smem + 64 * 65,
                        vis_b, txt_b, b1 + (size_t)e * 1024, b1t + (size_t)e * 1024);
    } else if (id < 7872) {
        // frag-pack w2 (K=1024,N=1024)
        const int i = id - 5824;
        const int kx = i & 15, ny = (i >> 4) & 15, e = i >> 8;
        frag_body<false>(w2 + (size_t)e * 1024 * 1024, w2t + (size_t)e * 1024 * 1024,
                         1024, kx * 64, ny * 64, tid, smem, smem + 64 * 65,
                         nullptr, nullptr, nullptr, nullptr);
    } else {
        // gcat: Gcat[v][j] = sum_d w_row[v][d]*gw[dglob][j]; v==1536 -> bg~
        const int v = id - 7872;
        const int lane = tid & 63, wv = tid >> 6;
        float a[8] = {0, 0, 0, 0, 0, 0, 0, 0};
        if (v < 1536) {
            const float* wr = (v < 768) ? vis_w + (size_t)v * 1024 : txt_w + (size_t)(v - 768) * 1024;
            const int dbase = (v < 768) ? 0 : 1024;
            for (int d = tid; d < 1024; d += 256) {
                const float c = wr[d];
                const float4* g4 = (const float4*)(gw + (size_t)(dbase + d) * 8);
                const float4 x = g4[0], y = g4[1];
                a[0] += c * x.x; a[1] += c * x.y; a[2] += c * x.z; a[3] += c * x.w;
                a[4] += c * y.x; a[5] += c * y.y; a[6] += c * y.z; a[7] += c * y.w;
            }
        } else {
            for (int d = tid; d < 2048; d += 256) {
                const float c = (d < 1024) ? vis_b[d] : txt_b[d - 1024];
                const float4* g4 = (const float4*)(gw + (size_t)d * 8);
                const float4 x = g4[0], y = g4[1];
                a[0] += c * x.x; a[1] += c * x.y; a[2] += c * x.z; a[3] += c * x.w;
                a[4] += c * y.x; a[5] += c * y.y; a[6] += c * y.z; a[7] += c * y.w;
            }
        }
#pragma unroll
        for (int j = 0; j < 8; ++j)
            for (int off = 32; off; off >>= 1) a[j] += __shfl_down(a[j], off, 64);
        float* red = smem;  // [4][8]
        if (lane == 0) {
#pragma unroll
            for (int j = 0; j < 8; ++j) red[wv * 8 + j] = a[j];
        }
        __syncthreads();
        if (tid < 8) {
            float s = red[tid] + red[8 + tid] + red[16 + tid] + red[24 + tid];
            if (v == 1536) s += gb[tid];
            gcat[(size_t)v * 8 + tid] = s;
        }
    }
}

#define MFMA32(a, b, c) __builtin_amdgcn_mfma_f32_32x32x16_bf16(a, b, c, 0, 0, 0)

// ---------------------------------------------------------------------------
// Core bf16 GEMM tile (round-0 schedule): C[128x128] = act(A @ W + bias).
// A in packed layout [mblk][K/8 chunks][128 rows][8]; W frag-packed
// B'[K/8][N][8] read straight to VGPRs. 2x2 waves x (2x2 mfma 32x32x16).
// PACK: 0 = row-major C; 1 = B-frag-packed C [M/8][N][8] (premul output);
//       2 = A-packed C [mblk][chunk][row][8] (feeds next GEMM's A).
// ---------------------------------------------------------------------------
template <int ACT, int PACK>
static __device__ __forceinline__ void gemm_core(const __bf16* __restrict__ A, int K,
                                                 const __bf16* __restrict__ Bt, int Bn,
                                                 const float* __restrict__ bias,
                                                 __bf16* __restrict__ C, int ldc,
                                                 int bm, int bn, __bf16* As) {
    const int tid = threadIdx.x;
    const int lane = tid & 63, wave = tid >> 6;
    const int wm = wave >> 1, wn = wave & 1;
    const int l = lane & 31, hi = lane >> 5;

    // A staging: packed source is linear -> coalesced 1KB/wave, linear dest.
    const __bf16* ag = A + (size_t)bm * K * 128 + (size_t)tid * 8;
    __bf16* asl = As + tid * 8;

    // A frag read: chunk (2s+hi)*1024 + (row wm*64 + mi*32 + l)*8; lane-contig.
    const __bf16* base_a = As + hi * 1024 + (wm * 64 + l) * 8;

    // B fragment base: frag(s,ni) at chunk kt*8+2s+hi, col bn*BN+wn*64+ni*32+l
    const size_t Bn8 = (size_t)Bn * 8;
    const __bf16* bbase = Bt + (size_t)hi * Bn8 + (size_t)(bn * BN + wn * 64 + l) * 8;
    const size_t bAdv = 8 * Bn8;

    f32x16_t acc[2][2] = {};

    const int nk = K / BK;
    for (int kt = 0; kt < nk; ++kt) {
        bf16x8_t bfr[4][2];
#pragma unroll
        for (int s = 0; s < 4; ++s) {
            bfr[s][0] = *(const bf16x8_t*)(bbase + (size_t)(2 * s) * Bn8);
            bfr[s][1] = *(const bf16x8_t*)(bbase + (size_t)(2 * s) * Bn8 + 256);
        }
        GLDS16(ag, asl);
        GLDS16(ag + 2048, asl + 2048);
        GLDS16(ag + 4096, asl + 4096);
        GLDS16(ag + 6144, asl + 6144);
        ag += 8192;
        bbase += bAdv;
        __syncthreads();
#pragma unroll
        for (int s = 0; s < 4; ++s) {
            const bf16x8_t a0 = *(const bf16x8_t*)(base_a + s * 2048);
            const bf16x8_t a1 = *(const bf16x8_t*)(base_a + s * 2048 + 256);
            acc[0][0] = MFMA32(a0, bfr[s][0], acc[0][0]);
            acc[0][1] = MFMA32(a0, bfr[s][1], acc[0][1]);
            acc[1][0] = MFMA32(a1, bfr[s][0], acc[1][0]);
            acc[1][1] = MFMA32(a1, bfr[s][1], acc[1][1]);
        }
        __syncthreads();
    }

    // epilogue: 32x32 C/D layout: col = lane&31, row = (reg&3)+8*(reg>>2)+4*hi
    const int colbase = bn * BN + wn * 64 + l;
    const int rowbase = bm * BM + wm * 64 + 4 * hi;
#pragma unroll
    for (int ni = 0; ni < 2; ++ni) {
        const int col = colbase + ni * 32;
        const float bv = (PACK == 1) ? 0.0f : bias[col];
#pragma unroll
        for (int mi = 0; mi < 2; ++mi) {
#pragma unroll
            for (int v = 0; v < 16; ++v) {
                const int row = rowbase + mi * 32 + (v & 3) + 8 * (v >> 2);
                float x = acc[mi][ni][v] + bv;
                if (ACT == 1) x = gelu_fast(x);
                if (PACK == 1) {
                    C[((size_t)(row >> 3)) * (size_t)ldc * 8 + (size_t)col * 8 + (row & 7)] = f2bf(x);
                } else if (PACK == 2) {
                    C[(size_t)(row >> 7) * (size_t)ldc * 128 + (size_t)(col >> 3) * 1024 +
                      (size_t)(row & 127) * 8 + (col & 7)] = f2bf(x);
                } else {
                    C[(size_t)row * ldc + col] = f2bf(x);
                }
            }
        }
    }
}

// 1D grid with bijective XCD swizzle: nwg = 512*Eg (divisible by 8);
// swz chunks give each XCD 4 (bn,z) B-panels (L2-resident), bm streams.
template <int ACT, int PACK>
__global__ __launch_bounds__(256, 4) void gemm_bt(const __bf16* __restrict__ Ab, int K, size_t strideAe,
                                                  const __bf16* __restrict__ Bb, int Bn, size_t strideBe,
                                                  const float* __restrict__ biasb, size_t strideBiasE,
                                                  __bf16* __restrict__ Cb, int ldc, size_t strideCe) {
    __shared__ __bf16 As[BM * BK];  // 16 KB
    const int bid = blockIdx.x;
    const int cpx = gridDim.x >> 3;
    const int swz = (bid & 7) * cpx + (bid >> 3);
    const int bm = swz & 63, bn = (swz >> 6) & 7, z = swz >> 9;
    gemm_core<ACT, PACK>(Ab + (size_t)z * strideAe, K,
                         Bb + (size_t)z * strideBe, Bn,
                         biasb + (size_t)z * strideBiasE,
                         Cb + (size_t)z * strideCe, ldc, bm, bn, As);
}

// ---------------------------------------------------------------------------
// premul (768 blocks, XCD-swizzled) + gate (128 blocks) in one launch.
// premul: W1cat = [vis_w@w1_top ; txt_w@w1_bot], frag-packed (PACK=1).
// gate: softmax(acat @ Gcat + bg~), 64 rows/block, coalesced packed reads.
// ---------------------------------------------------------------------------
__global__ __launch_bounds__(256, 4) void premul_gate(const __bf16* __restrict__ wbf,
                                                      const __bf16* __restrict__ w1t,
                                                      __bf16* __restrict__ w1cat,
                                                      const __bf16* __restrict__ acat,
                                                      const float* __restrict__ gcat,
                                                      float* __restrict__ gate) {
    __shared__ __align__(16) __bf16 As[BM * BK];  // 16 KB (gate uses 9.2 KB as float)
    const int id = blockIdx.x;
    const int tid = threadIdx.x;
    if (id < 768) {
        const int swz = (id & 7) * 96 + (id >> 3);
        const int bm = swz % 6;
        const int t1 = swz / 6;
        const int bn = t1 & 7;
        const int z = t1 >> 3;
        const int e = z & 7, hf = z >> 3;
        gemm_core<0, 1>(wbf + (size_t)hf * 786432, 1024,
                        w1t + (size_t)e * 2048 * 1024 + (size_t)hf * 128 * 1024 * 8, 1024,
                        nullptr,
                        w1cat + (size_t)e * 1536 * 1024 + (size_t)hf * 96 * 1024 * 8, 1024,
                        bm, bn, As);
    } else {
        const int bid = id - 768;
        const int lane = tid & 63, wv = tid >> 6;
        const int mblk = bid >> 1;
        const int rowIn = (bid & 1) * 64 + lane;
        const __bf16* base = acat + (size_t)mblk * 196608 + (size_t)rowIn * 8;
        float a[8] = {0, 0, 0, 0, 0, 0, 0, 0};
        for (int k = 0; k < 48; ++k) {
            const int c = wv + 4 * k;
            const bf16x8_t av = *(const bf16x8_t*)(base + (size_t)c * 1024);
            const float* g = gcat + (size_t)c * 64;
#pragma unroll
            for (int jj = 0; jj < 8; ++jj) {
                const float cf = bf2f(av[jj]);
                const float4 x = *(const float4*)(g + jj * 8);
                const float4 y = *(const float4*)(g + jj * 8 + 4);
                a[0] += cf * x.x; a[1] += cf * x.y; a[2] += cf * x.z; a[3] += cf * x.w;
                a[4] += cf * y.x; a[5] += cf * y.y; a[6] += cf * y.z; a[7] += cf * y.w;
            }
        }
        float* red = (float*)As;  // [4][64][9]
#pragma unroll
        for (int j = 0; j < 8; ++j) red[(wv * 64 + lane) * 9 + j] = a[j];
        __syncthreads();
        if (tid < 64) {
            const float* bg = gcat + 1536 * 8;
            float l[8];
            float m = -1e30f;
#pragma unroll
            for (int j = 0; j < 8; ++j) {
                l[j] = red[tid * 9 + j] + red[(64 + tid) * 9 + j] +
                       red[(128 + tid) * 9 + j] + red[(192 + tid) * 9 + j] + bg[j];
                m = fmaxf(m, l[j]);
            }
            float s = 0.f;
#pragma unroll
            for (int j = 0; j < 8; ++j) { l[j] = expf(l[j] - m); s += l[j]; }
            const float inv = 1.0f / s;
            const size_t r = (size_t)bid * 64 + tid;
#pragma unroll
            for (int j = 0; j < 8; ++j) gate[r * 8 + j] = l[j] * inv;
        }
    }
}

// ---------------------------------------------------------------------------
// Fused LayerNorm + gated expert reduction (h2 row-major).
// One WAVE per row (4 rows/block), no barriers; lane owns {q*256+lane*4+j}
// -> every global access lane-contiguous (R9-proven).
// ---------------------------------------------------------------------------
__global__ __launch_bounds__(256) void ln_out_kernel(const __bf16* __restrict__ h2,
                                                     const float* __restrict__ gate,
                                                     const float* __restrict__ lng,
                                                     const float* __restrict__ lnb,
                                                     float* __restrict__ out,
                                                     int Eg, int g0, int accum) {
    const int lane = threadIdx.x & 63;
    const int b = blockIdx.x * 4 + (threadIdx.x >> 6);
    const int d0 = lane * 4;                 // + q*256 per quad
    float* orow = out + (size_t)b * 1024 + d0;
    float o[16];
    if (accum) {
#pragma unroll
        for (int q = 0; q < 4; ++q) {
            const float4 p = *(const float4*)(orow + q * 256);
            o[q * 4 + 0] = p.x; o[q * 4 + 1] = p.y; o[q * 4 + 2] = p.z; o[q * 4 + 3] = p.w;
        }
    } else {
#pragma unroll
        for (int j = 0; j < 16; ++j) o[j] = 0.f;
    }
    for (int e = 0; e < Eg; ++e) {
        const __bf16* hp = h2 + ((size_t)e * 8192 + b) * 1024 + d0;
        float v[16];
#pragma unroll
        for (int q = 0; q < 4; ++q) {
            const bf16x4_t hv = *(const bf16x4_t*)(hp + q * 256);
            v[q * 4 + 0] = bf2f(hv[0]); v[q * 4 + 1] = bf2f(hv[1]);
            v[q * 4 + 2] = bf2f(hv[2]); v[q * 4 + 3] = bf2f(hv[3]);
        }
        float s = 0.f, ss = 0.f;
#pragma unroll
        for (int j = 0; j < 16; ++j) { s += v[j]; ss += v[j] * v[j]; }
#pragma unroll
        for (int off = 32; off; off >>= 1) {
            s += __shfl_xor(s, off, 64);
            ss += __shfl_xor(ss, off, 64);
        }
        const float mu = s * (1.0f / 1024.0f);
        const float var = ss * (1.0f / 1024.0f) - mu * mu;
        const float rstd = rsqrtf(var + 1e-5f);
        const float w = gate[(size_t)b * 8 + g0 + e];
        const float* gg = lng + (size_t)(g0 + e) * 1024 + d0;
        const float* bb = lnb + (size_t)(g0 + e) * 1024 + d0;
#pragma unroll
        for (int q = 0; q < 4; ++q) {
            const float4 g4 = *(const float4*)(gg + q * 256);
            const float4 b4 = *(const float4*)(bb + q * 256);
            o[q * 4 + 0] += w * ((v[q * 4 + 0] - mu) * rstd * g4.x + b4.x);
            o[q * 4 + 1] += w * ((v[q * 4 + 1] - mu) * rstd * g4.y + b4.y);
            o[q * 4 + 2] += w * ((v[q * 4 + 2] - mu) * rstd * g4.z + b4.z);
            o[q * 4 + 3] += w * ((v[q * 4 + 3] - mu) * rstd * g4.w + b4.w);
        }
    }
#pragma unroll
    for (int q = 0; q < 4; ++q)
        *(float4*)(orow + q * 256) = make_float4(o[q * 4], o[q * 4 + 1], o[q * 4 + 2], o[q * 4 + 3]);
}

// ---------------------------------------------------------------------------
extern "C" void kernel_launch(void* const* d_in, const int* in_sizes, int n_in,
                              void* d_out, int out_size, void* d_ws, size_t ws_size,
                              hipStream_t stream) {
    (void)in_sizes; (void)n_in; (void)out_size;
    const float* visual = (const float*)d_in[0];
    const float* text   = (const float*)d_in[1];
    const float* vis_w  = (const float*)d_in[2];
    const float* vis_b  = (const float*)d_in[3];
    const float* txt_w  = (const float*)d_in[4];
    const float* txt_b  = (const float*)d_in[5];
    const float* gate_w = (const float*)d_in[6];
    const float* gate_b = (const float*)d_in[7];
    const float* w1     = (const float*)d_in[8];
    const float* b1     = (const float*)d_in[9];
    const float* w2     = (const float*)d_in[10];
    const float* b2     = (const float*)d_in[11];
    const float* ln_g   = (const float*)d_in[12];
    const float* ln_b   = (const float*)d_in[13];
    float* out = (float*)d_out;

    const size_t B = 8192, DV = 768, D = 1024, G = 2048, E = 8, KC = 1536;

    char* ws = (char*)d_ws;
    size_t o = 0;
    auto alloc = [&](size_t bytes) { size_t r = o; o = (o + bytes + 255) & ~(size_t)255; return r; };
    const size_t off_wbf   = alloc(2 * DV * D * 2);        // packed vis_w | txt_w
    const size_t off_w1cat = alloc(E * KC * D * 2);        // fused W1, frag-packed
    const size_t off_w2t   = alloc(E * D * D * 2);
    const size_t off_b1t   = alloc(E * D * 4);
    const size_t off_gcat  = alloc((KC * E + E) * 4);
    const size_t off_gate  = alloc(B * E * 4);
    const size_t off_acat  = alloc(B * KC * 2);
    const size_t fixedEnd = o;
    const size_t w1tBytes = E * G * D * 2;  // 33.5 MB, dead after premul

    int Eg = 1;
    {
        const int cand[4] = {8, 4, 2, 1};
        for (int c = 0; c < 4; ++c) {
            size_t h2b = 2 * (size_t)cand[c] * B * D * 2;
            size_t dyn = h2b > w1tBytes ? h2b : w1tBytes;
            if (fixedEnd + dyn <= ws_size || cand[c] == 1) { Eg = cand[c]; break; }
        }
    }

    __bf16* wbf   = (__bf16*)(ws + off_wbf);
    __bf16* w1cat = (__bf16*)(ws + off_w1cat);
    __bf16* w2t   = (__bf16*)(ws + off_w2t);
    float*  b1t   = (float*)(ws + off_b1t);
    float*  gcat  = (float*)(ws + off_gcat);
    float*  gate  = (float*)(ws + off_gate);
    __bf16* acat  = (__bf16*)(ws + off_acat);
    __bf16* w1t   = (__bf16*)(ws + fixedEnd);              // aliased: dead after premul
    __bf16* h1    = (__bf16*)(ws + fixedEnd);              // overwrites w1t in expert loop
    __bf16* h2    = h1 + (size_t)Eg * B * D;

    // 1) fused front-end: all casts + frag-packs (+b1t) + gcat, one launch
    hipMemsetAsync(b1t, 0, E * D * 4, stream);
    front_kernel<<<9409, 256, 0, stream>>>(visual, text, vis_w, txt_w, w1, w2,
                                           vis_b, txt_b, b1, gate_w, gate_b,
                                           wbf, acat, w1t, w2t, b1t, gcat);

    // 2) premul (XCD-swizzled) + gate softmax, one launch
    premul_gate<<<896, 256, 0, stream>>>(wbf, w1t, w1cat, acat, gcat, gate);

    // 3) experts in groups of Eg: h1 = gelu(acat@W1cat + b1t) [A-packed out];
    //    h2 = h1@w2 + b2 [row-major out]; LN+reduce
    const int ng = 8 / Eg;
    for (int g = 0; g < ng; ++g) {
        const int g0 = g * Eg;
        gemm_bt<1, 2><<<512 * Eg, 256, 0, stream>>>(
            acat, (int)KC, 0, w1cat + (size_t)g0 * KC * D, (int)D, KC * D,
            b1t + (size_t)g0 * D, D, h1, (int)D, B * D);
        gemm_bt<0, 0><<<512 * Eg, 256, 0, stream>>>(
            h1, (int)D, B * D, w2t + (size_t)g0 * D * D, (int)D, D * D,
            b2 + (size_t)g0 * D, D, h2, (int)D, B * D);
        ln_out_kernel<<<(int)(B / 4), 256, 0, stream>>>(h2, gate, ln_g, ln_b, out, Eg, g0, g > 0 ? 1 : 0);
    }
}

// Round 12
// 700.558 us; speedup vs baseline: 1.0302x; 1.0302x over previous
//
#include <hip/hip_runtime.h>
#include <hip/hip_bf16.h>
#include <math.h>

// Round-0 proven 128x128x64 2-barrier GEMM structure with A pre-packed in
// tile-packed layout [mblk][chunk][row][8]:
//  - global_load_lds staging fully linear/coalesced (1KB/wave/instr)
//  - LDS frag reads lane-contiguous -> 0 bank conflicts (R5 PMC: 6.29M -> 0)
//  - __launch_bounds__(256,4): 60+64=124 regs < 128 -> 4 blocks/CU (occ 37%)
// R10: front-end fused into ONE kernel; gate merged into premul launch.
// R12: XCD swizzle REVERTED — R11 measured FETCH 108->394MB (swz re-streamed
// A per bn-sweep per XCD) yet dur only +5%: GEMM is NOT locality-bound, so
// natural bm-fastest order (108MB regime) is restored and the lever retired.
// NOTE: 8-phase/double-buffer schedules REGRESSED 3x (R1/R2/R4: 180/156/160us
// vs 135us) — multi-block/CU overlap beats lockstep pipelining. Do not re-add.
#define BM 128
#define BN 128
#define BK 64

typedef __bf16 bf16x8_t __attribute__((ext_vector_type(8)));
typedef __bf16 bf16x4_t __attribute__((ext_vector_type(4)));
typedef float f32x16_t __attribute__((ext_vector_type(16)));

static __device__ __forceinline__ float bf2f(__bf16 b) {
    unsigned short s = __builtin_bit_cast(unsigned short, b);
    unsigned int u = ((unsigned int)s) << 16;
    return __builtin_bit_cast(float, u);
}
static __device__ __forceinline__ __bf16 f2bf(float f) {
    unsigned int u = __builtin_bit_cast(unsigned int, f);
    unsigned int r = (u + 0x7fffu + ((u >> 16) & 1u)) >> 16;
    return __builtin_bit_cast(__bf16, (unsigned short)r);
}
// GELU tanh-form, |err vs exact| ~1e-3 << 4e-2 tolerance.
static __device__ __forceinline__ float gelu_fast(float x) {
    const float s = x * (0.7978845608f + 0.0356774081f * x * x);
    const float e = __expf(-2.0f * s);
    return x * __builtin_amdgcn_rcpf(1.0f + e);
}

#define GLDS16(gp, lp)                                                                   \
    __builtin_amdgcn_global_load_lds((const __attribute__((address_space(1))) void*)(gp), \
                                     (__attribute__((address_space(3))) void*)(lp), 16, 0, 0)

// ---------------------------------------------------------------------------
// Device bodies for the fused front-end kernel.
// ---------------------------------------------------------------------------

// fp32 W[K][N] tile (64x64 at k0,n0) -> bf16 B'[K/8][N][8]; optional fused
// b1t[n] += sum_k bcat[k]*W[k][n] (+ b1[n] on k0==0 block).
template <bool DOBIAS>
static __device__ __forceinline__ void frag_body(const float* __restrict__ in,
                                                 __bf16* __restrict__ out,
                                                 int N, int k0, int n0, int tid,
                                                 float* tile /*64x65*/, float* pb /*4x64*/,
                                                 const float* __restrict__ vb,
                                                 const float* __restrict__ tb,
                                                 const float* __restrict__ b1e,
                                                 float* __restrict__ b1te) {
    const int r = tid >> 4, c4 = (tid & 15) * 4;
#pragma unroll
    for (int p = 0; p < 4; ++p) {
        const float4 v = *(const float4*)&in[(size_t)(k0 + r + p * 16) * N + n0 + c4];
        float* t = tile + (r + p * 16) * 65 + c4;
        t[0] = v.x; t[1] = v.y; t[2] = v.z; t[3] = v.w;
    }
    __syncthreads();
    if (DOBIAS) {
        const int n = tid & 63, kq = tid >> 6;
        float p = 0.f;
#pragma unroll
        for (int rr = 0; rr < 16; ++rr) {
            const int kg = k0 + kq * 16 + rr;            // wave-uniform -> s_load
            const float bv = (kg < 1024) ? vb[kg] : tb[kg - 1024];
            p += bv * tile[(kq * 16 + rr) * 65 + n];
        }
        pb[kq * 64 + n] = p;
    }
    const int c = tid >> 5, nn0 = (tid & 31) * 2;
#pragma unroll
    for (int t = 0; t < 2; ++t) {
        const int nn = nn0 + t;
        bf16x8_t v;
#pragma unroll
        for (int j = 0; j < 8; ++j) v[j] = f2bf(tile[(c * 8 + j) * 65 + nn]);
        *(bf16x8_t*)&out[((size_t)(k0 >> 3) + c) * N * 8 + (size_t)(n0 + nn) * 8] = v;
    }
    if (DOBIAS) {
        __syncthreads();
        if (tid < 64) {
            float s = pb[tid] + pb[64 + tid] + pb[128 + tid] + pb[192 + tid];
            if (k0 == 0) s += b1e[n0 + tid];
            atomicAdd(&b1te[n0 + tid], s);
        }
    }
}

// 128x64 fp32 tile (row stride srcLd) -> A-packed bf16 at dst (+ch*1024+row*8).
static __device__ __forceinline__ void castpack_body(const float* __restrict__ src,
                                                     int srcLd, __bf16* __restrict__ dst,
                                                     int tid, __bf16* lds /*8*1032*/) {
#pragma unroll
    for (int k = 0; k < 8; ++k) {
        const int f = tid + k * 256;
        const int row = f >> 4, c4 = f & 15;
        const float4 v = *(const float4*)(src + (size_t)row * srcLd + c4 * 4);
        __bf16* d = lds + (c4 >> 1) * 1032 + row * 8 + (c4 & 1) * 4;
        d[0] = f2bf(v.x); d[1] = f2bf(v.y); d[2] = f2bf(v.z); d[3] = f2bf(v.w);
    }
    __syncthreads();
#pragma unroll
    for (int k = 0; k < 4; ++k) {
        const int g = tid + k * 256;
        const int ch = g >> 7, row = g & 127;
        const bf16x8_t v = *(const bf16x8_t*)(lds + ch * 1032 + row * 8);
        *(bf16x8_t*)(dst + (size_t)ch * 1024 + row * 8) = v;
    }
}

// ---------------------------------------------------------------------------
// Fused front-end: [0,192) cast2(wbf) | [192,1728) cast_acat | [1728,5824)
// frag w1 (+b1t) | [5824,7872) frag w2 | [7872,9409) gcat. All independent.
// ---------------------------------------------------------------------------
__global__ __launch_bounds__(256) void front_kernel(
    const float* __restrict__ visual, const float* __restrict__ text,
    const float* __restrict__ vis_w, const float* __restrict__ txt_w,
    const float* __restrict__ w1, const float* __restrict__ w2,
    const float* __restrict__ vis_b, const float* __restrict__ txt_b,
    const float* __restrict__ b1,
    const float* __restrict__ gw, const float* __restrict__ gb,
    __bf16* __restrict__ wbf, __bf16* __restrict__ acat,
    __bf16* __restrict__ w1t, __bf16* __restrict__ w2t,
    float* __restrict__ b1t, float* __restrict__ gcat) {
    __shared__ __align__(16) float smem[64 * 65 + 256];   // 17.7 KB union
    const int id = blockIdx.x;
    const int tid = threadIdx.x;
    if (id < 192) {
        // cast2: fp32 [768][1024] x2 -> A-packed wbf
        __bf16* lds = (__bf16*)smem;
        const int m = id / 96, r2 = id % 96;
        const int mb = r2 >> 4, ct = r2 & 15;
        const int c0 = ct * 64;
        const float* src = (m ? txt_w : vis_w) + (size_t)mb * 128 * 1024 + c0;
        __bf16* dst = wbf + (size_t)m * 786432 + (size_t)mb * 131072 + (size_t)(c0 >> 3) * 1024;
        castpack_body(src, 1024, dst, tid, lds);
    } else if (id < 1728) {
        // cast_acat: visual|text -> A-packed acat
        __bf16* lds = (__bf16*)smem;
        const int i = id - 192;
        const int ct = i % 24, mb = i / 24;
        const int c0 = ct * 64;
        const float* src = (c0 < 768) ? visual + (size_t)mb * 128 * 768 + c0
                                      : text + (size_t)mb * 128 * 768 + (c0 - 768);
        __bf16* dst = acat + (size_t)mb * 196608 + (size_t)(c0 >> 3) * 1024;
        castpack_body(src, 768, dst, tid, lds);
    } else if (id < 5824) {
        // frag-pack w1 (K=2048,N=1024) + fused b1t reduce
        const int i = id - 1728;
        const int kx = i & 31, ny = (i >> 5) & 15, e = i >> 9;
        frag_body<true>(w1 + (size_t)e * 2048 * 1024, w1t + (size_t)e * 2048 * 1024,
                        1024, kx * 64, ny * 64, tid, smem, smem + 64 * 65,
                        vis_b, txt_b, b1 + (size_t)e * 1024, b1t + (size_t)e * 1024);
    } else if (id < 7872) {
        // frag-pack w2 (K=1024,N=1024)
        const int i = id - 5824;
        const int kx = i & 15, ny = (i >> 4) & 15, e = i >> 8;
        frag_body<false>(w2 + (size_t)e * 1024 * 1024, w2t + (size_t)e * 1024 * 1024,
                         1024, kx * 64, ny * 64, tid, smem, smem + 64 * 65,
                         nullptr, nullptr, nullptr, nullptr);
    } else {
        // gcat: Gcat[v][j] = sum_d w_row[v][d]*gw[dglob][j]; v==1536 -> bg~
        const int v = id - 7872;
        const int lane = tid & 63, wv = tid >> 6;
        float a[8] = {0, 0, 0, 0, 0, 0, 0, 0};
        if (v < 1536) {
            const float* wr = (v < 768) ? vis_w + (size_t)v * 1024 : txt_w + (size_t)(v - 768) * 1024;
            const int dbase = (v < 768) ? 0 : 1024;
            for (int d = tid; d < 1024; d += 256) {
                const float c = wr[d];
                const float4* g4 = (const float4*)(gw + (size_t)(dbase + d) * 8);
                const float4 x = g4[0], y = g4[1];
                a[0] += c * x.x; a[1] += c * x.y; a[2] += c * x.z; a[3] += c * x.w;
                a[4] += c * y.x; a[5] += c * y.y; a[6] += c * y.z; a[7] += c * y.w;
            }
        } else {
            for (int d = tid; d < 2048; d += 256) {
                const float c = (d < 1024) ? vis_b[d] : txt_b[d - 1024];
                const float4* g4 = (const float4*)(gw + (size_t)d * 8);
                const float4 x = g4[0], y = g4[1];
                a[0] += c * x.x; a[1] += c * x.y; a[2] += c * x.z; a[3] += c * x.w;
                a[4] += c * y.x; a[5] += c * y.y; a[6] += c * y.z; a[7] += c * y.w;
            }
        }
#pragma unroll
        for (int j = 0; j < 8; ++j)
            for (int off = 32; off; off >>= 1) a[j] += __shfl_down(a[j], off, 64);
        float* red = smem;  // [4][8]
        if (lane == 0) {
#pragma unroll
            for (int j = 0; j < 8; ++j) red[wv * 8 + j] = a[j];
        }
        __syncthreads();
        if (tid < 8) {
            float s = red[tid] + red[8 + tid] + red[16 + tid] + red[24 + tid];
            if (v == 1536) s += gb[tid];
            gcat[(size_t)v * 8 + tid] = s;
        }
    }
}

#define MFMA32(a, b, c) __builtin_amdgcn_mfma_f32_32x32x16_bf16(a, b, c, 0, 0, 0)

// ---------------------------------------------------------------------------
// Core bf16 GEMM tile (round-0 schedule): C[128x128] = act(A @ W + bias).
// A in packed layout [mblk][K/8 chunks][128 rows][8]; W frag-packed
// B'[K/8][N][8] read straight to VGPRs. 2x2 waves x (2x2 mfma 32x32x16).
// PACK: 0 = row-major C; 1 = B-frag-packed C [M/8][N][8] (premul output);
//       2 = A-packed C [mblk][chunk][row][8] (feeds next GEMM's A).
// ---------------------------------------------------------------------------
template <int ACT, int PACK>
static __device__ __forceinline__ void gemm_core(const __bf16* __restrict__ A, int K,
                                                 const __bf16* __restrict__ Bt, int Bn,
                                                 const float* __restrict__ bias,
                                                 __bf16* __restrict__ C, int ldc,
                                                 int bm, int bn, __bf16* As) {
    const int tid = threadIdx.x;
    const int lane = tid & 63, wave = tid >> 6;
    const int wm = wave >> 1, wn = wave & 1;
    const int l = lane & 31, hi = lane >> 5;

    // A staging: packed source is linear -> coalesced 1KB/wave, linear dest.
    const __bf16* ag = A + (size_t)bm * K * 128 + (size_t)tid * 8;
    __bf16* asl = As + tid * 8;

    // A frag read: chunk (2s+hi)*1024 + (row wm*64 + mi*32 + l)*8; lane-contig.
    const __bf16* base_a = As + hi * 1024 + (wm * 64 + l) * 8;

    // B fragment base: frag(s,ni) at chunk kt*8+2s+hi, col bn*BN+wn*64+ni*32+l
    const size_t Bn8 = (size_t)Bn * 8;
    const __bf16* bbase = Bt + (size_t)hi * Bn8 + (size_t)(bn * BN + wn * 64 + l) * 8;
    const size_t bAdv = 8 * Bn8;

    f32x16_t acc[2][2] = {};

    const int nk = K / BK;
    for (int kt = 0; kt < nk; ++kt) {
        bf16x8_t bfr[4][2];
#pragma unroll
        for (int s = 0; s < 4; ++s) {
            bfr[s][0] = *(const bf16x8_t*)(bbase + (size_t)(2 * s) * Bn8);
            bfr[s][1] = *(const bf16x8_t*)(bbase + (size_t)(2 * s) * Bn8 + 256);
        }
        GLDS16(ag, asl);
        GLDS16(ag + 2048, asl + 2048);
        GLDS16(ag + 4096, asl + 4096);
        GLDS16(ag + 6144, asl + 6144);
        ag += 8192;
        bbase += bAdv;
        __syncthreads();
#pragma unroll
        for (int s = 0; s < 4; ++s) {
            const bf16x8_t a0 = *(const bf16x8_t*)(base_a + s * 2048);
            const bf16x8_t a1 = *(const bf16x8_t*)(base_a + s * 2048 + 256);
            acc[0][0] = MFMA32(a0, bfr[s][0], acc[0][0]);
            acc[0][1] = MFMA32(a0, bfr[s][1], acc[0][1]);
            acc[1][0] = MFMA32(a1, bfr[s][0], acc[1][0]);
            acc[1][1] = MFMA32(a1, bfr[s][1], acc[1][1]);
        }
        __syncthreads();
    }

    // epilogue: 32x32 C/D layout: col = lane&31, row = (reg&3)+8*(reg>>2)+4*hi
    const int colbase = bn * BN + wn * 64 + l;
    const int rowbase = bm * BM + wm * 64 + 4 * hi;
#pragma unroll
    for (int ni = 0; ni < 2; ++ni) {
        const int col = colbase + ni * 32;
        const float bv = (PACK == 1) ? 0.0f : bias[col];
#pragma unroll
        for (int mi = 0; mi < 2; ++mi) {
#pragma unroll
            for (int v = 0; v < 16; ++v) {
                const int row = rowbase + mi * 32 + (v & 3) + 8 * (v >> 2);
                float x = acc[mi][ni][v] + bv;
                if (ACT == 1) x = gelu_fast(x);
                if (PACK == 1) {
                    C[((size_t)(row >> 3)) * (size_t)ldc * 8 + (size_t)col * 8 + (row & 7)] = f2bf(x);
                } else if (PACK == 2) {
                    C[(size_t)(row >> 7) * (size_t)ldc * 128 + (size_t)(col >> 3) * 1024 +
                      (size_t)(row & 127) * 8 + (col & 7)] = f2bf(x);
                } else {
                    C[(size_t)row * ldc + col] = f2bf(x);
                }
            }
        }
    }
}

// 1D grid, natural decomposition (bm fastest — R9's measured-good order).
template <int ACT, int PACK>
__global__ __launch_bounds__(256, 4) void gemm_bt(const __bf16* __restrict__ Ab, int K, size_t strideAe,
                                                  const __bf16* __restrict__ Bb, int Bn, size_t strideBe,
                                                  const float* __restrict__ biasb, size_t strideBiasE,
                                                  __bf16* __restrict__ Cb, int ldc, size_t strideCe) {
    __shared__ __bf16 As[BM * BK];  // 16 KB
    const int bid = blockIdx.x;
    const int bm = bid & 63, bn = (bid >> 6) & 7, z = bid >> 9;
    gemm_core<ACT, PACK>(Ab + (size_t)z * strideAe, K,
                         Bb + (size_t)z * strideBe, Bn,
                         biasb + (size_t)z * strideBiasE,
                         Cb + (size_t)z * strideCe, ldc, bm, bn, As);
}

// ---------------------------------------------------------------------------
// premul (768 blocks, natural order) + gate (128 blocks) in one launch.
// premul: W1cat = [vis_w@w1_top ; txt_w@w1_bot], frag-packed (PACK=1).
// gate: softmax(acat @ Gcat + bg~), 64 rows/block, coalesced packed reads.
// ---------------------------------------------------------------------------
__global__ __launch_bounds__(256, 4) void premul_gate(const __bf16* __restrict__ wbf,
                                                      const __bf16* __restrict__ w1t,
                                                      __bf16* __restrict__ w1cat,
                                                      const __bf16* __restrict__ acat,
                                                      const float* __restrict__ gcat,
                                                      float* __restrict__ gate) {
    __shared__ __align__(16) __bf16 As[BM * BK];  // 16 KB (gate uses 9.2 KB as float)
    const int id = blockIdx.x;
    const int tid = threadIdx.x;
    if (id < 768) {
        const int bm = id % 6;
        const int t1 = id / 6;
        const int bn = t1 & 7;
        const int z = t1 >> 3;
        const int e = z & 7, hf = z >> 3;
        gemm_core<0, 1>(wbf + (size_t)hf * 786432, 1024,
                        w1t + (size_t)e * 2048 * 1024 + (size_t)hf * 128 * 1024 * 8, 1024,
                        nullptr,
                        w1cat + (size_t)e * 1536 * 1024 + (size_t)hf * 96 * 1024 * 8, 1024,
                        bm, bn, As);
    } else {
        const int bid = id - 768;
        const int lane = tid & 63, wv = tid >> 6;
        const int mblk = bid >> 1;
        const int rowIn = (bid & 1) * 64 + lane;
        const __bf16* base = acat + (size_t)mblk * 196608 + (size_t)rowIn * 8;
        float a[8] = {0, 0, 0, 0, 0, 0, 0, 0};
        for (int k = 0; k < 48; ++k) {
            const int c = wv + 4 * k;
            const bf16x8_t av = *(const bf16x8_t*)(base + (size_t)c * 1024);
            const float* g = gcat + (size_t)c * 64;
#pragma unroll
            for (int jj = 0; jj < 8; ++jj) {
                const float cf = bf2f(av[jj]);
                const float4 x = *(const float4*)(g + jj * 8);
                const float4 y = *(const float4*)(g + jj * 8 + 4);
                a[0] += cf * x.x; a[1] += cf * x.y; a[2] += cf * x.z; a[3] += cf * x.w;
                a[4] += cf * y.x; a[5] += cf * y.y; a[6] += cf * y.z; a[7] += cf * y.w;
            }
        }
        float* red = (float*)As;  // [4][64][9]
#pragma unroll
        for (int j = 0; j < 8; ++j) red[(wv * 64 + lane) * 9 + j] = a[j];
        __syncthreads();
        if (tid < 64) {
            const float* bg = gcat + 1536 * 8;
            float l[8];
            float m = -1e30f;
#pragma unroll
            for (int j = 0; j < 8; ++j) {
                l[j] = red[tid * 9 + j] + red[(64 + tid) * 9 + j] +
                       red[(128 + tid) * 9 + j] + red[(192 + tid) * 9 + j] + bg[j];
                m = fmaxf(m, l[j]);
            }
            float s = 0.f;
#pragma unroll
            for (int j = 0; j < 8; ++j) { l[j] = expf(l[j] - m); s += l[j]; }
            const float inv = 1.0f / s;
            const size_t r = (size_t)bid * 64 + tid;
#pragma unroll
            for (int j = 0; j < 8; ++j) gate[r * 8 + j] = l[j] * inv;
        }
    }
}

// ---------------------------------------------------------------------------
// Fused LayerNorm + gated expert reduction (h2 row-major).
// One WAVE per row (4 rows/block), no barriers; lane owns {q*256+lane*4+j}
// -> every global access lane-contiguous (R9-proven).
// ---------------------------------------------------------------------------
__global__ __launch_bounds__(256) void ln_out_kernel(const __bf16* __restrict__ h2,
                                                     const float* __restrict__ gate,
                                                     const float* __restrict__ lng,
                                                     const float* __restrict__ lnb,
                                                     float* __restrict__ out,
                                                     int Eg, int g0, int accum) {
    const int lane = threadIdx.x & 63;
    const int b = blockIdx.x * 4 + (threadIdx.x >> 6);
    const int d0 = lane * 4;                 // + q*256 per quad
    float* orow = out + (size_t)b * 1024 + d0;
    float o[16];
    if (accum) {
#pragma unroll
        for (int q = 0; q < 4; ++q) {
            const float4 p = *(const float4*)(orow + q * 256);
            o[q * 4 + 0] = p.x; o[q * 4 + 1] = p.y; o[q * 4 + 2] = p.z; o[q * 4 + 3] = p.w;
        }
    } else {
#pragma unroll
        for (int j = 0; j < 16; ++j) o[j] = 0.f;
    }
    for (int e = 0; e < Eg; ++e) {
        const __bf16* hp = h2 + ((size_t)e * 8192 + b) * 1024 + d0;
        float v[16];
#pragma unroll
        for (int q = 0; q < 4; ++q) {
            const bf16x4_t hv = *(const bf16x4_t*)(hp + q * 256);
            v[q * 4 + 0] = bf2f(hv[0]); v[q * 4 + 1] = bf2f(hv[1]);
            v[q * 4 + 2] = bf2f(hv[2]); v[q * 4 + 3] = bf2f(hv[3]);
        }
        float s = 0.f, ss = 0.f;
#pragma unroll
        for (int j = 0; j < 16; ++j) { s += v[j]; ss += v[j] * v[j]; }
#pragma unroll
        for (int off = 32; off; off >>= 1) {
            s += __shfl_xor(s, off, 64);
            ss += __shfl_xor(ss, off, 64);
        }
        const float mu = s * (1.0f / 1024.0f);
        const float var = ss * (1.0f / 1024.0f) - mu * mu;
        const float rstd = rsqrtf(var + 1e-5f);
        const float w = gate[(size_t)b * 8 + g0 + e];
        const float* gg = lng + (size_t)(g0 + e) * 1024 + d0;
        const float* bb = lnb + (size_t)(g0 + e) * 1024 + d0;
#pragma unroll
        for (int q = 0; q < 4; ++q) {
            const float4 g4 = *(const float4*)(gg + q * 256);
            const float4 b4 = *(const float4*)(bb + q * 256);
            o[q * 4 + 0] += w * ((v[q * 4 + 0] - mu) * rstd * g4.x + b4.x);
            o[q * 4 + 1] += w * ((v[q * 4 + 1] - mu) * rstd * g4.y + b4.y);
            o[q * 4 + 2] += w * ((v[q * 4 + 2] - mu) * rstd * g4.z + b4.z);
            o[q * 4 + 3] += w * ((v[q * 4 + 3] - mu) * rstd * g4.w + b4.w);
        }
    }
#pragma unroll
    for (int q = 0; q < 4; ++q)
        *(float4*)(orow + q * 256) = make_float4(o[q * 4], o[q * 4 + 1], o[q * 4 + 2], o[q * 4 + 3]);
}

// ---------------------------------------------------------------------------
extern "C" void kernel_launch(void* const* d_in, const int* in_sizes, int n_in,
                              void* d_out, int out_size, void* d_ws, size_t ws_size,
                              hipStream_t stream) {
    (void)in_sizes; (void)n_in; (void)out_size;
    const float* visual = (const float*)d_in[0];
    const float* text   = (const float*)d_in[1];
    const float* vis_w  = (const float*)d_in[2];
    const float* vis_b  = (const float*)d_in[3];
    const float* txt_w  = (const float*)d_in[4];
    const float* txt_b  = (const float*)d_in[5];
    const float* gate_w = (const float*)d_in[6];
    const float* gate_b = (const float*)d_in[7];
    const float* w1     = (const float*)d_in[8];
    const float* b1     = (const float*)d_in[9];
    const float* w2     = (const float*)d_in[10];
    const float* b2     = (const float*)d_in[11];
    const float* ln_g   = (const float*)d_in[12];
    const float* ln_b   = (const float*)d_in[13];
    float* out = (float*)d_out;

    const size_t B = 8192, DV = 768, D = 1024, G = 2048, E = 8, KC = 1536;

    char* ws = (char*)d_ws;
    size_t o = 0;
    auto alloc = [&](size_t bytes) { size_t r = o; o = (o + bytes + 255) & ~(size_t)255; return r; };
    const size_t off_wbf   = alloc(2 * DV * D * 2);        // packed vis_w | txt_w
    const size_t off_w1cat = alloc(E * KC * D * 2);        // fused W1, frag-packed
    const size_t off_w2t   = alloc(E * D * D * 2);
    const size_t off_b1t   = alloc(E * D * 4);
    const size_t off_gcat  = alloc((KC * E + E) * 4);
    const size_t off_gate  = alloc(B * E * 4);
    const size_t off_acat  = alloc(B * KC * 2);
    const size_t fixedEnd = o;
    const size_t w1tBytes = E * G * D * 2;  // 33.5 MB, dead after premul

    int Eg = 1;
    {
        const int cand[4] = {8, 4, 2, 1};
        for (int c = 0; c < 4; ++c) {
            size_t h2b = 2 * (size_t)cand[c] * B * D * 2;
            size_t dyn = h2b > w1tBytes ? h2b : w1tBytes;
            if (fixedEnd + dyn <= ws_size || cand[c] == 1) { Eg = cand[c]; break; }
        }
    }

    __bf16* wbf   = (__bf16*)(ws + off_wbf);
    __bf16* w1cat = (__bf16*)(ws + off_w1cat);
    __bf16* w2t   = (__bf16*)(ws + off_w2t);
    float*  b1t   = (float*)(ws + off_b1t);
    float*  gcat  = (float*)(ws + off_gcat);
    float*  gate  = (float*)(ws + off_gate);
    __bf16* acat  = (__bf16*)(ws + off_acat);
    __bf16* w1t   = (__bf16*)(ws + fixedEnd);              // aliased: dead after premul
    __bf16* h1    = (__bf16*)(ws + fixedEnd);              // overwrites w1t in expert loop
    __bf16* h2    = h1 + (size_t)Eg * B * D;

    // 1) fused front-end: all casts + frag-packs (+b1t) + gcat, one launch
    hipMemsetAsync(b1t, 0, E * D * 4, stream);
    front_kernel<<<9409, 256, 0, stream>>>(visual, text, vis_w, txt_w, w1, w2,
                                           vis_b, txt_b, b1, gate_w, gate_b,
                                           wbf, acat, w1t, w2t, b1t, gcat);

    // 2) premul + gate softmax, one launch
    premul_gate<<<896, 256, 0, stream>>>(wbf, w1t, w1cat, acat, gcat, gate);

    // 3) experts in groups of Eg: h1 = gelu(acat@W1cat + b1t) [A-packed out];
    //    h2 = h1@w2 + b2 [row-major out]; LN+reduce
    const int ng = 8 / Eg;
    for (int g = 0; g < ng; ++g) {
        const int g0 = g * Eg;
        gemm_bt<1, 2><<<512 * Eg, 256, 0, stream>>>(
            acat, (int)KC, 0, w1cat + (size_t)g0 * KC * D, (int)D, KC * D,
            b1t + (size_t)g0 * D, D, h1, (int)D, B * D);
        gemm_bt<0, 0><<<512 * Eg, 256, 0, stream>>>(
            h1, (int)D, B * D, w2t + (size_t)g0 * D * D, (int)D, D * D,
            b2 + (size_t)g0 * D, D, h2, (int)D, B * D);
        ln_out_kernel<<<(int)(B / 4), 256, 0, stream>>>(h2, gate, ln_g, ln_b, out, Eg, g0, g > 0 ? 1 : 0);
    }
}